// Round 9
// baseline (459.895 us; speedup 1.0000x reference)
//
#include <hip/hip_runtime.h>
#include <math.h>

// UnifiedCortexGPT — bf16 MFMA + bsearch top-K + gather-based column reduce.
// B=4096, D=512, C=16, K_sel=204.

#define KSEL 204

typedef unsigned short u16;
typedef __attribute__((ext_vector_type(8))) short bf16x8;
typedef __attribute__((ext_vector_type(4))) float f32x4;
typedef __attribute__((ext_vector_type(8))) unsigned short u16x8;

__device__ __forceinline__ float gelu_f(float x) {
  return 0.5f * x * (1.0f + erff(x * 0.70710678118654752f));
}
__device__ __forceinline__ u16 f2b(float f) {  // RNE fp32->bf16
  unsigned u = __float_as_uint(f);
  u += 0x7fff + ((u >> 16) & 1);
  return (u16)(u >> 16);
}
__device__ __forceinline__ float b2f(u16 b) {
  return __uint_as_float(((unsigned)b) << 16);
}

#define GLOAD_LDS(gsrc, ldst)                                                  \
  __builtin_amdgcn_global_load_lds(                                            \
      (const __attribute__((address_space(1))) void*)(gsrc),                   \
      (__attribute__((address_space(3))) void*)(ldst), 16, 0, 0)

// ---------------- transpose-convert: src[K][N] f32 -> dst[N][K] bf16 ----------
__global__ __launch_bounds__(256) void transpose_b_k(
    const float* __restrict__ src, u16* __restrict__ dst, int K, int N) {
  __shared__ float t[32][33];
  const size_t mz = (size_t)blockIdx.z * K * N;
  int k0 = blockIdx.y * 32, n0 = blockIdx.x * 32;
  int r = threadIdx.x >> 5, c = threadIdx.x & 31;
#pragma unroll
  for (int i = 0; i < 4; i++)
    t[r + 8 * i][c] = src[mz + (size_t)(k0 + r + 8 * i) * N + n0 + c];
  __syncthreads();
#pragma unroll
  for (int i = 0; i < 4; i++)
    dst[mz + (size_t)(n0 + r + 8 * i) * K + k0 + c] = f2b(t[c][r + 8 * i]);
}

// ---------------- elementwise f32 -> bf16 ----------------
__global__ __launch_bounds__(256) void cvt_k(const float* __restrict__ src,
                                             u16* __restrict__ dst, int n4) {
  int i = blockIdx.x * 256 + threadIdx.x;
  if (i < n4) {
    float4 v = ((const float4*)src)[i];
    ushort4 o;
    o.x = f2b(v.x); o.y = f2b(v.y); o.z = f2b(v.z); o.w = f2b(v.w);
    ((ushort4*)dst)[i] = o;
  }
}

// ================= MFMA GEMM template =================
// A [M][K] bf16 (K contig), Bt [N][K] bf16 (K contig), tile 128(M)x64(N), BK=64.
// 256 thr = 4 waves 2x2: wave(wm,wn) owns rows wm*64+[0,64), cols wn*32+[0,32).
// EPI: 0 = gelu -> bf16 out (ldOutB)    1 = gelu -> f32 out (stride N)
//      2 = gate: sigmoid(acc+bias); h = g*mix + (1-g)*x -> f32 + bf16
//      3 = gelu -> f32 out, rows >= Mvalid masked
template <int EPI>
__global__ __launch_bounds__(256) void mgemm_k(
    const u16* __restrict__ A, const u16* __restrict__ Bt,
    const float* __restrict__ bias, float* __restrict__ outF,
    u16* __restrict__ outB, int ldOutB, const float* __restrict__ xres,
    int M, int N, int K, int Mvalid,
    long szA, long szB, long szBias, long szOutF) {
  __shared__ __align__(16) u16 As[128 * 64];  // 16KB
  __shared__ __align__(16) u16 Bs[64 * 64];   // 8KB
  const int tid = threadIdx.x;
  const int wid = tid >> 6, lane = tid & 63;
  const int wm = wid & 1, wn = wid >> 1;
  const int row0 = blockIdx.y * 128, col0 = blockIdx.x * 64;
  const size_t z = blockIdx.z;
  const u16* Ap = A + z * szA;
  const u16* Bp = Bt + z * szB;
  const float* biasp = bias + z * szBias;

  const int srow = tid >> 3;
  const int sslot = (tid & 7) ^ (srow & 7);

  f32x4 acc[4][2];
#pragma unroll
  for (int mi = 0; mi < 4; mi++)
#pragma unroll
    for (int ni = 0; ni < 2; ni++) acc[mi][ni] = (f32x4){0.f, 0.f, 0.f, 0.f};

  const int q = lane >> 4, rl = lane & 15;

  for (int k0 = 0; k0 < K; k0 += 64) {
#pragma unroll
    for (int i = 0; i < 4; i++) {
      const u16* src = Ap + (size_t)(row0 + i * 32 + srow) * K + k0 + sslot * 8;
      GLOAD_LDS(src, (char*)As + i * 4096 + wid * 1024);
    }
#pragma unroll
    for (int i = 0; i < 2; i++) {
      const u16* src = Bp + (size_t)(col0 + i * 32 + srow) * K + k0 + sslot * 8;
      GLOAD_LDS(src, (char*)Bs + i * 4096 + wid * 1024);
    }
    __syncthreads();
#pragma unroll
    for (int h = 0; h < 2; h++) {
      bf16x8 af[4], bfr[2];
#pragma unroll
      for (int mi = 0; mi < 4; mi++) {
        int row = wm * 64 + mi * 16 + rl;
        int slot = (h * 4 + q) ^ (row & 7);
        af[mi] = *(const bf16x8*)((const char*)As + row * 128 + slot * 16);
      }
#pragma unroll
      for (int ni = 0; ni < 2; ni++) {
        int n = wn * 32 + ni * 16 + rl;
        int slot = (h * 4 + q) ^ (n & 7);
        bfr[ni] = *(const bf16x8*)((const char*)Bs + n * 128 + slot * 16);
      }
#pragma unroll
      for (int mi = 0; mi < 4; mi++)
#pragma unroll
        for (int ni = 0; ni < 2; ni++)
          acc[mi][ni] = __builtin_amdgcn_mfma_f32_16x16x32_bf16(
              af[mi], bfr[ni], acc[mi][ni], 0, 0, 0);
    }
    __syncthreads();
  }

  // epilogue: C frag layout col = lane&15, row = (lane>>4)*4 + r
#pragma unroll
  for (int ni = 0; ni < 2; ni++) {
    const int col = col0 + wn * 32 + ni * 16 + rl;
    const float bv = biasp[col];
#pragma unroll
    for (int mi = 0; mi < 4; mi++) {
#pragma unroll
      for (int r = 0; r < 4; r++) {
        const int row = row0 + wm * 64 + mi * 16 + q * 4 + r;
        float v = acc[mi][ni][r] + bv;
        if (EPI == 0) {
          outB[(size_t)row * ldOutB + col] = f2b(gelu_f(v));
        } else if (EPI == 1) {
          (outF + z * szOutF)[(size_t)row * N + col] = gelu_f(v);
        } else if (EPI == 2) {
          float g = 1.f / (1.f + expf(-v));
          float fa = b2f(Ap[(size_t)row * 1024 + col]);
          float sl = b2f(Ap[(size_t)row * 1024 + 512 + col]);
          float xv = xres[(size_t)row * 512 + col];
          float hv = g * (0.91f * fa + 0.09f * sl) + (1.f - g) * xv;
          outF[(size_t)row * 512 + col] = hv;
          outB[(size_t)row * 512 + col] = f2b(hv);
        } else {  // EPI == 3
          if (row < Mvalid)
            (outF + z * szOutF)[(size_t)row * N + col] = gelu_f(v);
        }
      }
    }
  }
}

// ---------- column GEMM 1 with row gather: p1bf[c] = gelu_bf16(h[sel] @ cw1T[c]) ----------
__global__ __launch_bounds__(256) void mgemm_col1_k(
    const u16* __restrict__ hbf, const u16* __restrict__ cw1T,
    const float* __restrict__ cb1, u16* __restrict__ p1bf,
    const int* __restrict__ selidx) {
  const int N = 1024, K = 512;
  __shared__ __align__(16) u16 As[128 * 64];
  __shared__ __align__(16) u16 Bs[64 * 64];
  const int tid = threadIdx.x;
  const int wid = tid >> 6, lane = tid & 63;
  const int wm = wid & 1, wn = wid >> 1;
  const int row0 = blockIdx.y * 128, col0 = blockIdx.x * 64;
  const int c = blockIdx.z;
  const u16* Bp = cw1T + (size_t)c * N * K;
  const float* biasp = cb1 + (size_t)c * N;
  u16* outp = p1bf + (size_t)c * 256 * N;
  const int* rmap = selidx + c * 256;

  const int srow = tid >> 3;
  const int sslot = (tid & 7) ^ (srow & 7);
  int gr[4];
#pragma unroll
  for (int i = 0; i < 4; i++) {
    int rli = row0 + i * 32 + srow;
    gr[i] = (rli < KSEL) ? rmap[rli] : 0;
  }

  f32x4 acc[4][2];
#pragma unroll
  for (int mi = 0; mi < 4; mi++)
#pragma unroll
    for (int ni = 0; ni < 2; ni++) acc[mi][ni] = (f32x4){0.f, 0.f, 0.f, 0.f};
  const int q = lane >> 4, rl = lane & 15;

  for (int k0 = 0; k0 < K; k0 += 64) {
#pragma unroll
    for (int i = 0; i < 4; i++) {
      const u16* src = hbf + (size_t)gr[i] * 512 + k0 + sslot * 8;
      GLOAD_LDS(src, (char*)As + i * 4096 + wid * 1024);
    }
#pragma unroll
    for (int i = 0; i < 2; i++) {
      const u16* src = Bp + (size_t)(col0 + i * 32 + srow) * K + k0 + sslot * 8;
      GLOAD_LDS(src, (char*)Bs + i * 4096 + wid * 1024);
    }
    __syncthreads();
#pragma unroll
    for (int h = 0; h < 2; h++) {
      bf16x8 af[4], bfr[2];
#pragma unroll
      for (int mi = 0; mi < 4; mi++) {
        int row = wm * 64 + mi * 16 + rl;
        int slot = (h * 4 + q) ^ (row & 7);
        af[mi] = *(const bf16x8*)((const char*)As + row * 128 + slot * 16);
      }
#pragma unroll
      for (int ni = 0; ni < 2; ni++) {
        int n = wn * 32 + ni * 16 + rl;
        int slot = (h * 4 + q) ^ (n & 7);
        bfr[ni] = *(const bf16x8*)((const char*)Bs + n * 128 + slot * 16);
      }
#pragma unroll
      for (int mi = 0; mi < 4; mi++)
#pragma unroll
        for (int ni = 0; ni < 2; ni++)
          acc[mi][ni] = __builtin_amdgcn_mfma_f32_16x16x32_bf16(
              af[mi], bfr[ni], acc[mi][ni], 0, 0, 0);
    }
    __syncthreads();
  }

#pragma unroll
  for (int ni = 0; ni < 2; ni++) {
    const int col = col0 + wn * 32 + ni * 16 + rl;
    const float bv = biasp[col];
#pragma unroll
    for (int mi = 0; mi < 4; mi++) {
#pragma unroll
      for (int r = 0; r < 4; r++) {
        const int row = row0 + wm * 64 + mi * 16 + q * 4 + r;
        if (row < KSEL)
          outp[(size_t)row * N + col] = f2b(gelu_f(acc[mi][ni][r] + bv));
      }
    }
  }
}

// ---------------- LayerNorm 512 f32 -> bf16 (slow path) ----------------
__global__ __launch_bounds__(256) void ln512bf_k(
    const float* __restrict__ in, const float* __restrict__ g,
    const float* __restrict__ b, u16* __restrict__ out, int nrows) {
  int wave = threadIdx.x >> 6, lane = threadIdx.x & 63;
  int row = blockIdx.x * 4 + wave;
  if (row >= nrows) return;
  const float4* r4 = (const float4*)(in + (size_t)row * 512);
  float4 v0 = r4[lane * 2], v1 = r4[lane * 2 + 1];
  float s = v0.x + v0.y + v0.z + v0.w + v1.x + v1.y + v1.z + v1.w;
#pragma unroll
  for (int o = 32; o; o >>= 1) s += __shfl_xor(s, o);
  float mean = s * (1.0f / 512.0f);
  float qv = 0.f;
  {
    float dx;
    dx = v0.x - mean; qv += dx * dx;  dx = v0.y - mean; qv += dx * dx;
    dx = v0.z - mean; qv += dx * dx;  dx = v0.w - mean; qv += dx * dx;
    dx = v1.x - mean; qv += dx * dx;  dx = v1.y - mean; qv += dx * dx;
    dx = v1.z - mean; qv += dx * dx;  dx = v1.w - mean; qv += dx * dx;
  }
#pragma unroll
  for (int o = 32; o; o >>= 1) qv += __shfl_xor(qv, o);
  float rstd = rsqrtf(qv * (1.0f / 512.0f) + 1e-5f);
  const float4* g4 = (const float4*)g;
  const float4* b4 = (const float4*)b;
  float4 gg0 = g4[lane * 2], gg1 = g4[lane * 2 + 1];
  float4 bb0 = b4[lane * 2], bb1 = b4[lane * 2 + 1];
  u16x8 o8;
  o8[0] = f2b((v0.x - mean) * rstd * gg0.x + bb0.x);
  o8[1] = f2b((v0.y - mean) * rstd * gg0.y + bb0.y);
  o8[2] = f2b((v0.z - mean) * rstd * gg0.z + bb0.z);
  o8[3] = f2b((v0.w - mean) * rstd * gg0.w + bb0.w);
  o8[4] = f2b((v1.x - mean) * rstd * gg1.x + bb1.x);
  o8[5] = f2b((v1.y - mean) * rstd * gg1.y + bb1.y);
  o8[6] = f2b((v1.z - mean) * rstd * gg1.z + bb1.z);
  o8[7] = f2b((v1.w - mean) * rstd * gg1.w + bb1.w);
  *(u16x8*)(out + (size_t)row * 512 + lane * 8) = o8;
}

// ---------------- LayerNorm 1024 in-place on bf16 p1, per-column g/b ----------------
__global__ __launch_bounds__(256) void ln1024bf_k(
    u16* __restrict__ p, const float* __restrict__ g,
    const float* __restrict__ b) {
  int wave = threadIdx.x >> 6, lane = threadIdx.x & 63;
  int row = blockIdx.x * 4 + wave;
  int c = blockIdx.y;
  if (row >= KSEL) return;
  u16* rp = p + ((size_t)c * 256 + row) * 1024 + lane * 16;
  u16x8 a0 = *(const u16x8*)rp;
  u16x8 a1 = *(const u16x8*)(rp + 8);
  float f[16];
#pragma unroll
  for (int j = 0; j < 8; j++) { f[j] = b2f(a0[j]); f[8 + j] = b2f(a1[j]); }
  float s = 0.f;
#pragma unroll
  for (int j = 0; j < 16; j++) s += f[j];
#pragma unroll
  for (int o = 32; o; o >>= 1) s += __shfl_xor(s, o);
  float mean = s * (1.0f / 1024.0f);
  float qv = 0.f;
#pragma unroll
  for (int j = 0; j < 16; j++) { float d = f[j] - mean; qv += d * d; }
#pragma unroll
  for (int o = 32; o; o >>= 1) qv += __shfl_xor(qv, o);
  float rstd = rsqrtf(qv * (1.0f / 1024.0f) + 1e-5f);
  const float* gp = g + (size_t)c * 1024 + lane * 16;
  const float* bp = b + (size_t)c * 1024 + lane * 16;
  u16x8 o0, o1;
#pragma unroll
  for (int j = 0; j < 8; j++)
    o0[j] = f2b((f[j] - mean) * rstd * gp[j] + bp[j]);
#pragma unroll
  for (int j = 0; j < 8; j++)
    o1[j] = f2b((f[8 + j] - mean) * rstd * gp[8 + j] + bp[8 + j]);
  *(u16x8*)rp = o0;
  *(u16x8*)(rp + 8) = o1;
}

// ---------- LayerNorm 512 on p2 f32, per-column g/b, DENSE write to p2n ----------
__global__ __launch_bounds__(256) void ln512n_k(
    const float* __restrict__ p2, const float* __restrict__ g,
    const float* __restrict__ b, float* __restrict__ p2n) {
  int wave = threadIdx.x >> 6, lane = threadIdx.x & 63;
  int row = blockIdx.x * 4 + wave;
  int c = blockIdx.y;
  if (row >= KSEL) return;
  const float4* r4 = (const float4*)(p2 + ((size_t)c * 256 + row) * 512);
  float4 v0 = r4[lane * 2], v1 = r4[lane * 2 + 1];
  float s = v0.x + v0.y + v0.z + v0.w + v1.x + v1.y + v1.z + v1.w;
#pragma unroll
  for (int o = 32; o; o >>= 1) s += __shfl_xor(s, o);
  float mean = s * (1.0f / 512.0f);
  float qv = 0.f;
  {
    float dx;
    dx = v0.x - mean; qv += dx * dx;  dx = v0.y - mean; qv += dx * dx;
    dx = v0.z - mean; qv += dx * dx;  dx = v0.w - mean; qv += dx * dx;
    dx = v1.x - mean; qv += dx * dx;  dx = v1.y - mean; qv += dx * dx;
    dx = v1.z - mean; qv += dx * dx;  dx = v1.w - mean; qv += dx * dx;
  }
#pragma unroll
  for (int o = 32; o; o >>= 1) qv += __shfl_xor(qv, o);
  float rstd = rsqrtf(qv * (1.0f / 512.0f) + 1e-5f);
  const float4* g4 = (const float4*)(g + (size_t)c * 512);
  const float4* b4 = (const float4*)(b + (size_t)c * 512);
  float4 gg0 = g4[lane * 2], gg1 = g4[lane * 2 + 1];
  float4 bb0 = b4[lane * 2], bb1 = b4[lane * 2 + 1];
  float4 o0, o1;
  o0.x = (v0.x - mean) * rstd * gg0.x + bb0.x;
  o0.y = (v0.y - mean) * rstd * gg0.y + bb0.y;
  o0.z = (v0.z - mean) * rstd * gg0.z + bb0.z;
  o0.w = (v0.w - mean) * rstd * gg0.w + bb0.w;
  o1.x = (v1.x - mean) * rstd * gg1.x + bb1.x;
  o1.y = (v1.y - mean) * rstd * gg1.y + bb1.y;
  o1.z = (v1.z - mean) * rstd * gg1.z + bb1.z;
  o1.w = (v1.w - mean) * rstd * gg1.w + bb1.w;
  float4* w4 = (float4*)(p2n + ((size_t)c * 256 + row) * 512);
  w4[lane * 2] = o0;
  w4[lane * 2 + 1] = o1;
}

// ---------------- scores[c][b] = h[b] . colg_w[c] + colg_b[c] ----------------
__global__ __launch_bounds__(256) void scores_k(
    const float* __restrict__ h, const float* __restrict__ cw,
    const float* __restrict__ cb, float* __restrict__ scores) {
  int wave = threadIdx.x >> 6, lane = threadIdx.x & 63;
  int b = blockIdx.x * 4 + wave;
  const float4* hr = (const float4*)(h + (size_t)b * 512);
  float4 h0 = hr[lane * 2], h1 = hr[lane * 2 + 1];
#pragma unroll
  for (int c = 0; c < 16; c++) {
    const float4* w4 = (const float4*)(cw + (size_t)c * 512);
    float4 w0 = w4[lane * 2], w1 = w4[lane * 2 + 1];
    float acc = h0.x * w0.x + h0.y * w0.y + h0.z * w0.z + h0.w * w0.w +
                h1.x * w1.x + h1.y * w1.y + h1.z * w1.z + h1.w * w1.w;
#pragma unroll
    for (int o = 32; o; o >>= 1) acc += __shfl_xor(acc, o);
    if (lane == 0) scores[c * 4096 + b] = acc + cb[c];
  }
}

// -------- exact top-K via 32-step binary search; parallel tie handling --------
// also records inverse map posmap[c][b] = compact row index (-1 if unselected)
__global__ __launch_bounds__(256) void select_bsearch_k(
    const float* __restrict__ scores, int* __restrict__ selcnt,
    int* __restrict__ selidx, int* __restrict__ posmap) {
  const int c = blockIdx.x;
  const int t = threadIdx.x;
  const int w = t >> 6, lane = t & 63;
  __shared__ unsigned keys[4096];
  __shared__ int wc[2][4];
  unsigned k[16];
#pragma unroll
  for (int i = 0; i < 16; i++) {
    unsigned u = __float_as_uint(scores[c * 4096 + t + 256 * i]);
    u = (u & 0x80000000u) ? ~u : (u | 0x80000000u);  // monotonic key
    k[i] = u;
    keys[t + 256 * i] = u;
  }
  __syncthreads();
  // find T = K-th largest key: max T s.t. count(>=T) >= KSEL
  unsigned lo = 0u, hi = 0xFFFFFFFFu;
  for (int it = 0; it < 32; ++it) {
    const unsigned mid = hi - ((hi - lo) >> 1);  // upper mid, no overflow
    int cnt = 0;
#pragma unroll
    for (int i = 0; i < 16; i++) cnt += (k[i] >= mid);
#pragma unroll
    for (int o = 32; o; o >>= 1) cnt += __shfl_xor(cnt, o);
    if (lane == 0) wc[it & 1][w] = cnt;
    __syncthreads();
    const int tot = wc[it & 1][0] + wc[it & 1][1] + wc[it & 1][2] + wc[it & 1][3];
    if (tot >= KSEL) lo = mid; else hi = mid - 1;  // identical on all threads
  }
  const unsigned T = lo;
  // packed block-wide counts: (count_gt << 16) | count_eq
  {
    int cg = 0, ce = 0;
#pragma unroll
    for (int i = 0; i < 16; i++) { cg += (k[i] > T); ce += (k[i] == T); }
    int packed = (cg << 16) | ce;
#pragma unroll
    for (int o = 32; o; o >>= 1) packed += __shfl_xor(packed, o);
    if (lane == 0) wc[0][w] = packed;
  }
  __syncthreads();
  const int ptot = wc[0][0] + wc[0][1] + wc[0][2] + wc[0][3];
  const int count_gt = ptot >> 16;
  const int count_eq = ptot & 0xFFFF;
  const int need_eq = KSEL - count_gt;               // 1 <= need_eq <= count_eq
  const bool take_all_ties = (count_eq == need_eq);  // true for distinct scores
#pragma unroll
  for (int i = 0; i < 16; i++) {
    const int b = t + 256 * i;
    bool sel = (k[i] > T);
    if (k[i] == T) {
      if (take_all_ties) {
        sel = true;
      } else {  // genuine duplicate threshold: rank ties by lower index (rare)
        int r = 0;
        for (int j = 0; j < b; j++) r += (keys[j] == T);
        sel = (r < need_eq);
      }
    }
    if (sel) {
      int pos = atomicAdd(&selcnt[c], 1);
      selidx[c * 256 + pos] = b;
      posmap[c * 4096 + b] = pos;
    }
  }
}

// ---------------- out[b] = h[b] + 0.00625 * sum_c p2n[c][posmap[c][b]] ----------------
__global__ __launch_bounds__(256) void final_gather_k(
    const float* __restrict__ h, const float* __restrict__ p2n,
    const int* __restrict__ posmap, float* __restrict__ out) {
  int wave = threadIdx.x >> 6, lane = threadIdx.x & 63;
  int b = blockIdx.x * 4 + wave;
  float4 a0 = {0.f, 0.f, 0.f, 0.f}, a1 = {0.f, 0.f, 0.f, 0.f};
#pragma unroll
  for (int c = 0; c < 16; c++) {
    int pos = posmap[c * 4096 + b];  // wave-uniform
    if (pos >= 0) {
      const float4* r = (const float4*)(p2n + ((size_t)c * 256 + pos) * 512);
      float4 v0 = r[lane * 2], v1 = r[lane * 2 + 1];
      a0.x += v0.x; a0.y += v0.y; a0.z += v0.z; a0.w += v0.w;
      a1.x += v1.x; a1.y += v1.y; a1.z += v1.z; a1.w += v1.w;
    }
  }
  const float4* hr = (const float4*)(h + (size_t)b * 512);
  float4 h0 = hr[lane * 2], h1 = hr[lane * 2 + 1];
  float4 o0, o1;
  o0.x = h0.x + 0.00625f * a0.x;  o0.y = h0.y + 0.00625f * a0.y;
  o0.z = h0.z + 0.00625f * a0.z;  o0.w = h0.w + 0.00625f * a0.w;
  o1.x = h1.x + 0.00625f * a1.x;  o1.y = h1.y + 0.00625f * a1.y;
  o1.z = h1.z + 0.00625f * a1.z;  o1.w = h1.w + 0.00625f * a1.w;
  float4* w4 = (float4*)(out + (size_t)b * 512);
  w4[lane * 2] = o0;
  w4[lane * 2 + 1] = o1;
}

extern "C" void kernel_launch(void* const* d_in, const int* in_sizes, int n_in,
                              void* d_out, int out_size, void* d_ws,
                              size_t ws_size, hipStream_t stream) {
  const float* x = (const float*)d_in[0];
  const float* fw1 = (const float*)d_in[1];
  const float* fb1 = (const float*)d_in[2];
  const float* fw2 = (const float*)d_in[3];
  const float* fb2 = (const float*)d_in[4];
  const float* sw1 = (const float*)d_in[5];
  const float* sb1 = (const float*)d_in[6];
  const float* sg = (const float*)d_in[7];
  const float* sbeta = (const float*)d_in[8];
  const float* sw2 = (const float*)d_in[9];
  const float* sb2 = (const float*)d_in[10];
  const float* gw = (const float*)d_in[11];
  const float* gb = (const float*)d_in[12];
  const float* cw1 = (const float*)d_in[13];
  const float* cb1 = (const float*)d_in[14];
  const float* cg1 = (const float*)d_in[15];
  const float* cbe1 = (const float*)d_in[16];
  const float* cw2 = (const float*)d_in[17];
  const float* cb2 = (const float*)d_in[18];
  const float* cg2 = (const float*)d_in[19];
  const float* cbe2 = (const float*)d_in[20];
  const float* cgw = (const float*)d_in[21];
  const float* cgb = (const float*)d_in[22];

  char* ws = (char*)d_ws;
  u16* cw1T  = (u16*)(ws + 0);           // 16 MB  [16][1024][512]
  u16* cw2T  = (u16*)(ws + 16777216);    // 16 MB  [16][512][1024]
  u16* fw1T  = (u16*)(ws + 33554432);    // 1 MB   [1024][512]
  u16* fw2T  = (u16*)(ws + 34603008);    // 1 MB   [512][1024]
  u16* sw1T  = (u16*)(ws + 35651584);    // 512 KB [512][512]
  u16* sw2T  = (u16*)(ws + 36175872);    // 512 KB
  u16* gwT   = (u16*)(ws + 36700160);    // 1 MB   [512][1024]
  u16* xbf   = (u16*)(ws + 37748736);    // 4 MB   [4096][512]
  u16* s1nbf = (u16*)(ws + 41943040);    // 4 MB
  u16* y1bf  = (u16*)(ws + 46137344);    // 8 MB   [4096][1024]
  float* s1f = (float*)(ws + 54525952);  // 8 MB   [4096][512]
  u16* hcat  = (u16*)(ws + 62914560);    // 8 MB   [4096][1024] fast|slow
  float* hF  = (float*)(ws + 71303168);  // 8 MB
  u16* hbf   = (u16*)(ws + 79691776);    // 4 MB
  float* scores = (float*)(ws + 83886080);   // 256 KB
  int* selidx = (int*)(ws + 84148224);       // 16 KB
  int* selcnt = (int*)(ws + 84164608);       // 64 B
  // overlays (liveness-checked):
  float* p2n  = (float*)(ws + 37748736);  // 8 MB over xbf+s1nbf (dead after G3/G4)
  u16* p1bf   = (u16*)(ws + 46137344);    // over y1bf (dead after G2)
  float* p2   = (float*)(ws + 54525952);  // over s1f (dead after LN512)
  int* posmap = (int*)(ws + 62914560);    // 256 KB over hcat (dead after G5)

  dim3 blk(256);
  hipMemsetAsync(selcnt, 0, 64, stream);
  // weight transposes + x convert
  cvt_k<<<2048, blk, 0, stream>>>(x, xbf, 524288);
  transpose_b_k<<<dim3(32, 16, 1), blk, 0, stream>>>(fw1, fw1T, 512, 1024);
  transpose_b_k<<<dim3(16, 32, 1), blk, 0, stream>>>(fw2, fw2T, 1024, 512);
  transpose_b_k<<<dim3(16, 16, 1), blk, 0, stream>>>(sw1, sw1T, 512, 512);
  transpose_b_k<<<dim3(16, 16, 1), blk, 0, stream>>>(sw2, sw2T, 512, 512);
  transpose_b_k<<<dim3(16, 32, 1), blk, 0, stream>>>(gw, gwT, 1024, 512);
  transpose_b_k<<<dim3(32, 16, 16), blk, 0, stream>>>(cw1, cw1T, 512, 1024);
  transpose_b_k<<<dim3(16, 32, 16), blk, 0, stream>>>(cw2, cw2T, 1024, 512);

  // G1: y1 = gelu(x @ fw1)            [4096,1024] bf16
  mgemm_k<0><<<dim3(16, 32, 1), blk, 0, stream>>>(
      xbf, fw1T, fb1, nullptr, y1bf, 1024, nullptr, 4096, 1024, 512, 4096, 0, 0, 0, 0);
  // G2: fast = gelu(y1 @ fw2) -> hcat[:, :512] bf16
  mgemm_k<0><<<dim3(8, 32, 1), blk, 0, stream>>>(
      y1bf, fw2T, fb2, nullptr, hcat, 1024, nullptr, 4096, 512, 1024, 4096, 0, 0, 0, 0);
  // G3: s1 = gelu(x @ sw1)            f32
  mgemm_k<1><<<dim3(8, 32, 1), blk, 0, stream>>>(
      xbf, sw1T, sb1, s1f, nullptr, 0, nullptr, 4096, 512, 512, 4096, 0, 0, 0, 0);
  ln512bf_k<<<1024, blk, 0, stream>>>(s1f, sg, sbeta, s1nbf, 4096);
  // G4: slow = gelu(s1n @ sw2) -> hcat[:, 512:] bf16
  mgemm_k<0><<<dim3(8, 32, 1), blk, 0, stream>>>(
      s1nbf, sw2T, sb2, nullptr, hcat + 512, 1024, nullptr, 4096, 512, 512, 4096, 0, 0, 0, 0);
  // G5: gate + mix + blend -> hF f32, hbf bf16
  mgemm_k<2><<<dim3(8, 32, 1), blk, 0, stream>>>(
      hcat, gwT, gb, hF, hbf, 512, x, 4096, 512, 1024, 4096, 0, 0, 0, 0);
  // posmap overlay (hcat dead after G5): -1 everywhere
  hipMemsetAsync(posmap, 0xFF, 262144, stream);
  // scores + exact top-K (binary search, parallel tie handling)
  scores_k<<<1024, blk, 0, stream>>>(hF, cgw, cgb, scores);
  select_bsearch_k<<<16, blk, 0, stream>>>(scores, selcnt, selidx, posmap);
  // columns (sparse rows only)
  mgemm_col1_k<<<dim3(16, 2, 16), blk, 0, stream>>>(hbf, cw1T, cb1, p1bf, selidx);
  ln1024bf_k<<<dim3(51, 16), blk, 0, stream>>>(p1bf, cg1, cbe1);
  mgemm_k<3><<<dim3(8, 2, 16), blk, 0, stream>>>(
      p1bf, cw2T, cb2, p2, nullptr, 0, nullptr, 256, 512, 1024, KSEL,
      256L * 1024, 512L * 1024, 512, 256L * 512);
  // LN(p2) -> dense p2n (no atomics)
  ln512n_k<<<dim3(51, 16), blk, 0, stream>>>(p2, cg2, cbe2, p2n);
  // out = h + 0.00625 * gather-sum over columns
  final_gather_k<<<1024, blk, 0, stream>>>(hF, p2n, posmap, (float*)d_out);
}

// Round 12
// 370.535 us; speedup vs baseline: 1.2412x; 1.2412x over previous
//
#include <hip/hip_runtime.h>
#include <math.h>

// UnifiedCortexGPT — bf16 MFMA + bsearch top-K + gather reduce
// + double-buffered (2-phase, counted-vmcnt) GEMM pipeline.
// B=4096, D=512, C=16, K_sel=204.

#define KSEL 204

typedef unsigned short u16;
typedef __attribute__((ext_vector_type(8))) short bf16x8;
typedef __attribute__((ext_vector_type(4))) float f32x4;
typedef __attribute__((ext_vector_type(8))) unsigned short u16x8;

__device__ __forceinline__ float gelu_f(float x) {
  return 0.5f * x * (1.0f + erff(x * 0.70710678118654752f));
}
__device__ __forceinline__ u16 f2b(float f) {  // RNE fp32->bf16
  unsigned u = __float_as_uint(f);
  u += 0x7fff + ((u >> 16) & 1);
  return (u16)(u >> 16);
}
__device__ __forceinline__ float b2f(u16 b) {
  return __uint_as_float(((unsigned)b) << 16);
}

#define GLOAD_LDS(gsrc, ldst)                                                  \
  __builtin_amdgcn_global_load_lds(                                            \
      (const __attribute__((address_space(1))) void*)(gsrc),                   \
      (__attribute__((address_space(3))) void*)(ldst), 16, 0, 0)

// ---------------- transpose-convert: src[K][N] f32 -> dst[N][K] bf16 ----------
__global__ __launch_bounds__(256) void transpose_b_k(
    const float* __restrict__ src, u16* __restrict__ dst, int K, int N) {
  __shared__ float t[32][33];
  const size_t mz = (size_t)blockIdx.z * K * N;
  int k0 = blockIdx.y * 32, n0 = blockIdx.x * 32;
  int r = threadIdx.x >> 5, c = threadIdx.x & 31;
#pragma unroll
  for (int i = 0; i < 4; i++)
    t[r + 8 * i][c] = src[mz + (size_t)(k0 + r + 8 * i) * N + n0 + c];
  __syncthreads();
#pragma unroll
  for (int i = 0; i < 4; i++)
    dst[mz + (size_t)(n0 + r + 8 * i) * K + k0 + c] = f2b(t[c][r + 8 * i]);
}

// ---------------- elementwise f32 -> bf16 ----------------
__global__ __launch_bounds__(256) void cvt_k(const float* __restrict__ src,
                                             u16* __restrict__ dst, int n4) {
  int i = blockIdx.x * 256 + threadIdx.x;
  if (i < n4) {
    float4 v = ((const float4*)src)[i];
    ushort4 o;
    o.x = f2b(v.x); o.y = f2b(v.y); o.z = f2b(v.z); o.w = f2b(v.w);
    ((ushort4*)dst)[i] = o;
  }
}

// ================= MFMA GEMM template (2-phase dbuf pipeline) =================
// A [M][K] bf16, Bt [N][K] bf16, tile 128(M)x64(N), BK=64, 4 waves 2x2.
// Per K-step: stage NEXT tile, s_waitcnt vmcnt(6) (counted — prefetch stays in
// flight), raw s_barrier, ds_read+MFMA current, raw s_barrier.
// EPI: 0 gelu->bf16 | 1 gelu->f32 | 2 gate epilogue | 3 gelu->f32 row-masked
template <int EPI>
__global__ __launch_bounds__(256) void mgemm_k(
    const u16* __restrict__ A, const u16* __restrict__ Bt,
    const float* __restrict__ bias, float* __restrict__ outF,
    u16* __restrict__ outB, int ldOutB, const float* __restrict__ xres,
    int M, int N, int K, int Mvalid,
    long szA, long szB, long szBias, long szOutF) {
  __shared__ __align__(16) u16 As[2][128 * 64];  // 32KB
  __shared__ __align__(16) u16 Bs[2][64 * 64];   // 16KB
  const int tid = threadIdx.x;
  const int wid = tid >> 6, lane = tid & 63;
  const int wm = wid & 1, wn = wid >> 1;
  const int row0 = blockIdx.y * 128, col0 = blockIdx.x * 64;
  const size_t z = blockIdx.z;
  const u16* Ap = A + z * szA;
  const u16* Bp = Bt + z * szB;
  const float* biasp = bias + z * szBias;

  const int srow = tid >> 3;
  const int sslot = (tid & 7) ^ (srow & 7);

  f32x4 acc[4][2];
#pragma unroll
  for (int mi = 0; mi < 4; mi++)
#pragma unroll
    for (int ni = 0; ni < 2; ni++) acc[mi][ni] = (f32x4){0.f, 0.f, 0.f, 0.f};

  const int q = lane >> 4, rl = lane & 15;
  const int nt = K >> 6;

  // prologue: stage tile 0 -> buf 0 (6 global_load_lds per wave)
#pragma unroll
  for (int i = 0; i < 4; i++) {
    const u16* src = Ap + (size_t)(row0 + i * 32 + srow) * K + sslot * 8;
    GLOAD_LDS(src, (char*)As + i * 4096 + wid * 1024);
  }
#pragma unroll
  for (int i = 0; i < 2; i++) {
    const u16* src = Bp + (size_t)(col0 + i * 32 + srow) * K + sslot * 8;
    GLOAD_LDS(src, (char*)Bs + i * 4096 + wid * 1024);
  }

  for (int t = 0; t < nt; ++t) {
    const int cur = t & 1;
    if (t + 1 < nt) {
      const int k0 = (t + 1) << 6;
      char* Ad = (char*)As + (cur ^ 1) * 16384;
      char* Bd = (char*)Bs + (cur ^ 1) * 8192;
#pragma unroll
      for (int i = 0; i < 4; i++) {
        const u16* src = Ap + (size_t)(row0 + i * 32 + srow) * K + k0 + sslot * 8;
        GLOAD_LDS(src, Ad + i * 4096 + wid * 1024);
      }
#pragma unroll
      for (int i = 0; i < 2; i++) {
        const u16* src = Bp + (size_t)(col0 + i * 32 + srow) * K + k0 + sslot * 8;
        GLOAD_LDS(src, Bd + i * 4096 + wid * 1024);
      }
      asm volatile("s_waitcnt vmcnt(6)" ::: "memory");  // cur's 6 retired
    } else {
      asm volatile("s_waitcnt vmcnt(0)" ::: "memory");
    }
    __builtin_amdgcn_s_barrier();
    const char* Ar = (const char*)As + cur * 16384;
    const char* Br = (const char*)Bs + cur * 8192;
#pragma unroll
    for (int h = 0; h < 2; h++) {
      bf16x8 af[4], bfr[2];
#pragma unroll
      for (int mi = 0; mi < 4; mi++) {
        int row = wm * 64 + mi * 16 + rl;
        int slot = (h * 4 + q) ^ (row & 7);
        af[mi] = *(const bf16x8*)(Ar + row * 128 + slot * 16);
      }
#pragma unroll
      for (int ni = 0; ni < 2; ni++) {
        int n = wn * 32 + ni * 16 + rl;
        int slot = (h * 4 + q) ^ (n & 7);
        bfr[ni] = *(const bf16x8*)(Br + n * 128 + slot * 16);
      }
#pragma unroll
      for (int mi = 0; mi < 4; mi++)
#pragma unroll
        for (int ni = 0; ni < 2; ni++)
          acc[mi][ni] = __builtin_amdgcn_mfma_f32_16x16x32_bf16(
              af[mi], bfr[ni], acc[mi][ni], 0, 0, 0);
    }
    if (t + 1 < nt) __builtin_amdgcn_s_barrier();  // reads done before overwrite
  }

  // epilogue: C frag layout col = lane&15, row = (lane>>4)*4 + r
#pragma unroll
  for (int ni = 0; ni < 2; ni++) {
    const int col = col0 + wn * 32 + ni * 16 + rl;
    const float bv = biasp[col];
#pragma unroll
    for (int mi = 0; mi < 4; mi++) {
#pragma unroll
      for (int r = 0; r < 4; r++) {
        const int row = row0 + wm * 64 + mi * 16 + q * 4 + r;
        float v = acc[mi][ni][r] + bv;
        if (EPI == 0) {
          outB[(size_t)row * ldOutB + col] = f2b(gelu_f(v));
        } else if (EPI == 1) {
          (outF + z * szOutF)[(size_t)row * N + col] = gelu_f(v);
        } else if (EPI == 2) {
          float g = 1.f / (1.f + expf(-v));
          float fa = b2f(Ap[(size_t)row * 1024 + col]);
          float sl = b2f(Ap[(size_t)row * 1024 + 512 + col]);
          float xv = xres[(size_t)row * 512 + col];
          float hv = g * (0.91f * fa + 0.09f * sl) + (1.f - g) * xv;
          outF[(size_t)row * 512 + col] = hv;
          outB[(size_t)row * 512 + col] = f2b(hv);
        } else {  // EPI == 3
          if (row < Mvalid)
            (outF + z * szOutF)[(size_t)row * N + col] = gelu_f(v);
        }
      }
    }
  }
}

// ---------- column GEMM 1 with row gather (same 2-phase pipeline) ----------
__global__ __launch_bounds__(256) void mgemm_col1_k(
    const u16* __restrict__ hbf, const u16* __restrict__ cw1T,
    const float* __restrict__ cb1, u16* __restrict__ p1bf,
    const int* __restrict__ selidx) {
  const int N = 1024, K = 512;
  __shared__ __align__(16) u16 As[2][128 * 64];
  __shared__ __align__(16) u16 Bs[2][64 * 64];
  const int tid = threadIdx.x;
  const int wid = tid >> 6, lane = tid & 63;
  const int wm = wid & 1, wn = wid >> 1;
  const int row0 = blockIdx.y * 128, col0 = blockIdx.x * 64;
  const int c = blockIdx.z;
  const u16* Bp = cw1T + (size_t)c * N * K;
  const float* biasp = cb1 + (size_t)c * N;
  u16* outp = p1bf + (size_t)c * 256 * N;
  const int* rmap = selidx + c * 256;

  const int srow = tid >> 3;
  const int sslot = (tid & 7) ^ (srow & 7);
  int gr[4];
#pragma unroll
  for (int i = 0; i < 4; i++) {
    int rli = row0 + i * 32 + srow;
    gr[i] = (rli < KSEL) ? rmap[rli] : 0;
  }

  f32x4 acc[4][2];
#pragma unroll
  for (int mi = 0; mi < 4; mi++)
#pragma unroll
    for (int ni = 0; ni < 2; ni++) acc[mi][ni] = (f32x4){0.f, 0.f, 0.f, 0.f};
  const int q = lane >> 4, rl = lane & 15;
  const int nt = K >> 6;  // 8

  // prologue: tile 0 -> buf 0
#pragma unroll
  for (int i = 0; i < 4; i++) {
    const u16* src = hbf + (size_t)gr[i] * 512 + sslot * 8;
    GLOAD_LDS(src, (char*)As + i * 4096 + wid * 1024);
  }
#pragma unroll
  for (int i = 0; i < 2; i++) {
    const u16* src = Bp + (size_t)(col0 + i * 32 + srow) * K + sslot * 8;
    GLOAD_LDS(src, (char*)Bs + i * 4096 + wid * 1024);
  }

  for (int t = 0; t < nt; ++t) {
    const int cur = t & 1;
    if (t + 1 < nt) {
      const int k0 = (t + 1) << 6;
      char* Ad = (char*)As + (cur ^ 1) * 16384;
      char* Bd = (char*)Bs + (cur ^ 1) * 8192;
#pragma unroll
      for (int i = 0; i < 4; i++) {
        const u16* src = hbf + (size_t)gr[i] * 512 + k0 + sslot * 8;
        GLOAD_LDS(src, Ad + i * 4096 + wid * 1024);
      }
#pragma unroll
      for (int i = 0; i < 2; i++) {
        const u16* src = Bp + (size_t)(col0 + i * 32 + srow) * K + k0 + sslot * 8;
        GLOAD_LDS(src, Bd + i * 4096 + wid * 1024);
      }
      asm volatile("s_waitcnt vmcnt(6)" ::: "memory");
    } else {
      asm volatile("s_waitcnt vmcnt(0)" ::: "memory");
    }
    __builtin_amdgcn_s_barrier();
    const char* Ar = (const char*)As + cur * 16384;
    const char* Br = (const char*)Bs + cur * 8192;
#pragma unroll
    for (int h = 0; h < 2; h++) {
      bf16x8 af[4], bfr[2];
#pragma unroll
      for (int mi = 0; mi < 4; mi++) {
        int row = wm * 64 + mi * 16 + rl;
        int slot = (h * 4 + q) ^ (row & 7);
        af[mi] = *(const bf16x8*)(Ar + row * 128 + slot * 16);
      }
#pragma unroll
      for (int ni = 0; ni < 2; ni++) {
        int n = wn * 32 + ni * 16 + rl;
        int slot = (h * 4 + q) ^ (n & 7);
        bfr[ni] = *(const bf16x8*)(Br + n * 128 + slot * 16);
      }
#pragma unroll
      for (int mi = 0; mi < 4; mi++)
#pragma unroll
        for (int ni = 0; ni < 2; ni++)
          acc[mi][ni] = __builtin_amdgcn_mfma_f32_16x16x32_bf16(
              af[mi], bfr[ni], acc[mi][ni], 0, 0, 0);
    }
    if (t + 1 < nt) __builtin_amdgcn_s_barrier();
  }

#pragma unroll
  for (int ni = 0; ni < 2; ni++) {
    const int col = col0 + wn * 32 + ni * 16 + rl;
    const float bv = biasp[col];
#pragma unroll
    for (int mi = 0; mi < 4; mi++) {
#pragma unroll
      for (int r = 0; r < 4; r++) {
        const int row = row0 + wm * 64 + mi * 16 + q * 4 + r;
        if (row < KSEL)
          outp[(size_t)row * N + col] = f2b(gelu_f(acc[mi][ni][r] + bv));
      }
    }
  }
}

// ---------------- LayerNorm 512 f32 -> bf16 (slow path) ----------------
__global__ __launch_bounds__(256) void ln512bf_k(
    const float* __restrict__ in, const float* __restrict__ g,
    const float* __restrict__ b, u16* __restrict__ out, int nrows) {
  int wave = threadIdx.x >> 6, lane = threadIdx.x & 63;
  int row = blockIdx.x * 4 + wave;
  if (row >= nrows) return;
  const float4* r4 = (const float4*)(in + (size_t)row * 512);
  float4 v0 = r4[lane * 2], v1 = r4[lane * 2 + 1];
  float s = v0.x + v0.y + v0.z + v0.w + v1.x + v1.y + v1.z + v1.w;
#pragma unroll
  for (int o = 32; o; o >>= 1) s += __shfl_xor(s, o);
  float mean = s * (1.0f / 512.0f);
  float qv = 0.f;
  {
    float dx;
    dx = v0.x - mean; qv += dx * dx;  dx = v0.y - mean; qv += dx * dx;
    dx = v0.z - mean; qv += dx * dx;  dx = v0.w - mean; qv += dx * dx;
    dx = v1.x - mean; qv += dx * dx;  dx = v1.y - mean; qv += dx * dx;
    dx = v1.z - mean; qv += dx * dx;  dx = v1.w - mean; qv += dx * dx;
  }
#pragma unroll
  for (int o = 32; o; o >>= 1) qv += __shfl_xor(qv, o);
  float rstd = rsqrtf(qv * (1.0f / 512.0f) + 1e-5f);
  const float4* g4 = (const float4*)g;
  const float4* b4 = (const float4*)b;
  float4 gg0 = g4[lane * 2], gg1 = g4[lane * 2 + 1];
  float4 bb0 = b4[lane * 2], bb1 = b4[lane * 2 + 1];
  u16x8 o8;
  o8[0] = f2b((v0.x - mean) * rstd * gg0.x + bb0.x);
  o8[1] = f2b((v0.y - mean) * rstd * gg0.y + bb0.y);
  o8[2] = f2b((v0.z - mean) * rstd * gg0.z + bb0.z);
  o8[3] = f2b((v0.w - mean) * rstd * gg0.w + bb0.w);
  o8[4] = f2b((v1.x - mean) * rstd * gg1.x + bb1.x);
  o8[5] = f2b((v1.y - mean) * rstd * gg1.y + bb1.y);
  o8[6] = f2b((v1.z - mean) * rstd * gg1.z + bb1.z);
  o8[7] = f2b((v1.w - mean) * rstd * gg1.w + bb1.w);
  *(u16x8*)(out + (size_t)row * 512 + lane * 8) = o8;
}

// ---------------- LayerNorm 1024 in-place on bf16 p1, per-column g/b ----------------
__global__ __launch_bounds__(256) void ln1024bf_k(
    u16* __restrict__ p, const float* __restrict__ g,
    const float* __restrict__ b) {
  int wave = threadIdx.x >> 6, lane = threadIdx.x & 63;
  int row = blockIdx.x * 4 + wave;
  int c = blockIdx.y;
  if (row >= KSEL) return;
  u16* rp = p + ((size_t)c * 256 + row) * 1024 + lane * 16;
  u16x8 a0 = *(const u16x8*)rp;
  u16x8 a1 = *(const u16x8*)(rp + 8);
  float f[16];
#pragma unroll
  for (int j = 0; j < 8; j++) { f[j] = b2f(a0[j]); f[8 + j] = b2f(a1[j]); }
  float s = 0.f;
#pragma unroll
  for (int j = 0; j < 16; j++) s += f[j];
#pragma unroll
  for (int o = 32; o; o >>= 1) s += __shfl_xor(s, o);
  float mean = s * (1.0f / 1024.0f);
  float qv = 0.f;
#pragma unroll
  for (int j = 0; j < 16; j++) { float d = f[j] - mean; qv += d * d; }
#pragma unroll
  for (int o = 32; o; o >>= 1) qv += __shfl_xor(qv, o);
  float rstd = rsqrtf(qv * (1.0f / 1024.0f) + 1e-5f);
  const float* gp = g + (size_t)c * 1024 + lane * 16;
  const float* bp = b + (size_t)c * 1024 + lane * 16;
  u16x8 o0, o1;
#pragma unroll
  for (int j = 0; j < 8; j++)
    o0[j] = f2b((f[j] - mean) * rstd * gp[j] + bp[j]);
#pragma unroll
  for (int j = 0; j < 8; j++)
    o1[j] = f2b((f[8 + j] - mean) * rstd * gp[8 + j] + bp[8 + j]);
  *(u16x8*)rp = o0;
  *(u16x8*)(rp + 8) = o1;
}

// ---------- LayerNorm 512 on p2 f32, per-column g/b, DENSE write to p2n ----------
__global__ __launch_bounds__(256) void ln512n_k(
    const float* __restrict__ p2, const float* __restrict__ g,
    const float* __restrict__ b, float* __restrict__ p2n) {
  int wave = threadIdx.x >> 6, lane = threadIdx.x & 63;
  int row = blockIdx.x * 4 + wave;
  int c = blockIdx.y;
  if (row >= KSEL) return;
  const float4* r4 = (const float4*)(p2 + ((size_t)c * 256 + row) * 512);
  float4 v0 = r4[lane * 2], v1 = r4[lane * 2 + 1];
  float s = v0.x + v0.y + v0.z + v0.w + v1.x + v1.y + v1.z + v1.w;
#pragma unroll
  for (int o = 32; o; o >>= 1) s += __shfl_xor(s, o);
  float mean = s * (1.0f / 512.0f);
  float qv = 0.f;
  {
    float dx;
    dx = v0.x - mean; qv += dx * dx;  dx = v0.y - mean; qv += dx * dx;
    dx = v0.z - mean; qv += dx * dx;  dx = v0.w - mean; qv += dx * dx;
    dx = v1.x - mean; qv += dx * dx;  dx = v1.y - mean; qv += dx * dx;
    dx = v1.z - mean; qv += dx * dx;  dx = v1.w - mean; qv += dx * dx;
  }
#pragma unroll
  for (int o = 32; o; o >>= 1) qv += __shfl_xor(qv, o);
  float rstd = rsqrtf(qv * (1.0f / 512.0f) + 1e-5f);
  const float4* g4 = (const float4*)(g + (size_t)c * 512);
  const float4* b4 = (const float4*)(b + (size_t)c * 512);
  float4 gg0 = g4[lane * 2], gg1 = g4[lane * 2 + 1];
  float4 bb0 = b4[lane * 2], bb1 = b4[lane * 2 + 1];
  float4 o0, o1;
  o0.x = (v0.x - mean) * rstd * gg0.x + bb0.x;
  o0.y = (v0.y - mean) * rstd * gg0.y + bb0.y;
  o0.z = (v0.z - mean) * rstd * gg0.z + bb0.z;
  o0.w = (v0.w - mean) * rstd * gg0.w + bb0.w;
  o1.x = (v1.x - mean) * rstd * gg1.x + bb1.x;
  o1.y = (v1.y - mean) * rstd * gg1.y + bb1.y;
  o1.z = (v1.z - mean) * rstd * gg1.z + bb1.z;
  o1.w = (v1.w - mean) * rstd * gg1.w + bb1.w;
  float4* w4 = (float4*)(p2n + ((size_t)c * 256 + row) * 512);
  w4[lane * 2] = o0;
  w4[lane * 2 + 1] = o1;
}

// ---------------- scores[c][b] = h[b] . colg_w[c] + colg_b[c] ----------------
__global__ __launch_bounds__(256) void scores_k(
    const float* __restrict__ h, const float* __restrict__ cw,
    const float* __restrict__ cb, float* __restrict__ scores) {
  int wave = threadIdx.x >> 6, lane = threadIdx.x & 63;
  int b = blockIdx.x * 4 + wave;
  const float4* hr = (const float4*)(h + (size_t)b * 512);
  float4 h0 = hr[lane * 2], h1 = hr[lane * 2 + 1];
#pragma unroll
  for (int c = 0; c < 16; c++) {
    const float4* w4 = (const float4*)(cw + (size_t)c * 512);
    float4 w0 = w4[lane * 2], w1 = w4[lane * 2 + 1];
    float acc = h0.x * w0.x + h0.y * w0.y + h0.z * w0.z + h0.w * w0.w +
                h1.x * w1.x + h1.y * w1.y + h1.z * w1.z + h1.w * w1.w;
#pragma unroll
    for (int o = 32; o; o >>= 1) acc += __shfl_xor(acc, o);
    if (lane == 0) scores[c * 4096 + b] = acc + cb[c];
  }
}

// -------- exact top-K via 32-step binary search; parallel tie handling --------
// also records inverse map posmap[c][b] = compact row index (-1 if unselected)
__global__ __launch_bounds__(256) void select_bsearch_k(
    const float* __restrict__ scores, int* __restrict__ selcnt,
    int* __restrict__ selidx, int* __restrict__ posmap) {
  const int c = blockIdx.x;
  const int t = threadIdx.x;
  const int w = t >> 6, lane = t & 63;
  __shared__ unsigned keys[4096];
  __shared__ int wc[2][4];
  unsigned k[16];
#pragma unroll
  for (int i = 0; i < 16; i++) {
    unsigned u = __float_as_uint(scores[c * 4096 + t + 256 * i]);
    u = (u & 0x80000000u) ? ~u : (u | 0x80000000u);  // monotonic key
    k[i] = u;
    keys[t + 256 * i] = u;
  }
  __syncthreads();
  // find T = K-th largest key: max T s.t. count(>=T) >= KSEL
  unsigned lo = 0u, hi = 0xFFFFFFFFu;
  for (int it = 0; it < 32; ++it) {
    const unsigned mid = hi - ((hi - lo) >> 1);  // upper mid, no overflow
    int cnt = 0;
#pragma unroll
    for (int i = 0; i < 16; i++) cnt += (k[i] >= mid);
#pragma unroll
    for (int o = 32; o; o >>= 1) cnt += __shfl_xor(cnt, o);
    if (lane == 0) wc[it & 1][w] = cnt;
    __syncthreads();
    const int tot = wc[it & 1][0] + wc[it & 1][1] + wc[it & 1][2] + wc[it & 1][3];
    if (tot >= KSEL) lo = mid; else hi = mid - 1;  // identical on all threads
  }
  const unsigned T = lo;
  // packed block-wide counts: (count_gt << 16) | count_eq
  {
    int cg = 0, ce = 0;
#pragma unroll
    for (int i = 0; i < 16; i++) { cg += (k[i] > T); ce += (k[i] == T); }
    int packed = (cg << 16) | ce;
#pragma unroll
    for (int o = 32; o; o >>= 1) packed += __shfl_xor(packed, o);
    if (lane == 0) wc[0][w] = packed;
  }
  __syncthreads();
  const int ptot = wc[0][0] + wc[0][1] + wc[0][2] + wc[0][3];
  const int count_gt = ptot >> 16;
  const int count_eq = ptot & 0xFFFF;
  const int need_eq = KSEL - count_gt;               // 1 <= need_eq <= count_eq
  const bool take_all_ties = (count_eq == need_eq);  // true for distinct scores
#pragma unroll
  for (int i = 0; i < 16; i++) {
    const int b = t + 256 * i;
    bool sel = (k[i] > T);
    if (k[i] == T) {
      if (take_all_ties) {
        sel = true;
      } else {  // genuine duplicate threshold: rank ties by lower index (rare)
        int r = 0;
        for (int j = 0; j < b; j++) r += (keys[j] == T);
        sel = (r < need_eq);
      }
    }
    if (sel) {
      int pos = atomicAdd(&selcnt[c], 1);
      selidx[c * 256 + pos] = b;
      posmap[c * 4096 + b] = pos;
    }
  }
}

// ---------------- out[b] = h[b] + 0.00625 * sum_c p2n[c][posmap[c][b]] ----------------
__global__ __launch_bounds__(256) void final_gather_k(
    const float* __restrict__ h, const float* __restrict__ p2n,
    const int* __restrict__ posmap, float* __restrict__ out) {
  int wave = threadIdx.x >> 6, lane = threadIdx.x & 63;
  int b = blockIdx.x * 4 + wave;
  float4 a0 = {0.f, 0.f, 0.f, 0.f}, a1 = {0.f, 0.f, 0.f, 0.f};
#pragma unroll
  for (int c = 0; c < 16; c++) {
    int pos = posmap[c * 4096 + b];  // wave-uniform
    if (pos >= 0) {
      const float4* r = (const float4*)(p2n + ((size_t)c * 256 + pos) * 512);
      float4 v0 = r[lane * 2], v1 = r[lane * 2 + 1];
      a0.x += v0.x; a0.y += v0.y; a0.z += v0.z; a0.w += v0.w;
      a1.x += v1.x; a1.y += v1.y; a1.z += v1.z; a1.w += v1.w;
    }
  }
  const float4* hr = (const float4*)(h + (size_t)b * 512);
  float4 h0 = hr[lane * 2], h1 = hr[lane * 2 + 1];
  float4 o0, o1;
  o0.x = h0.x + 0.00625f * a0.x;  o0.y = h0.y + 0.00625f * a0.y;
  o0.z = h0.z + 0.00625f * a0.z;  o0.w = h0.w + 0.00625f * a0.w;
  o1.x = h1.x + 0.00625f * a1.x;  o1.y = h1.y + 0.00625f * a1.y;
  o1.z = h1.z + 0.00625f * a1.z;  o1.w = h1.w + 0.00625f * a1.w;
  float4* w4 = (float4*)(out + (size_t)b * 512);
  w4[lane * 2] = o0;
  w4[lane * 2 + 1] = o1;
}

extern "C" void kernel_launch(void* const* d_in, const int* in_sizes, int n_in,
                              void* d_out, int out_size, void* d_ws,
                              size_t ws_size, hipStream_t stream) {
  const float* x = (const float*)d_in[0];
  const float* fw1 = (const float*)d_in[1];
  const float* fb1 = (const float*)d_in[2];
  const float* fw2 = (const float*)d_in[3];
  const float* fb2 = (const float*)d_in[4];
  const float* sw1 = (const float*)d_in[5];
  const float* sb1 = (const float*)d_in[6];
  const float* sg = (const float*)d_in[7];
  const float* sbeta = (const float*)d_in[8];
  const float* sw2 = (const float*)d_in[9];
  const float* sb2 = (const float*)d_in[10];
  const float* gw = (const float*)d_in[11];
  const float* gb = (const float*)d_in[12];
  const float* cw1 = (const float*)d_in[13];
  const float* cb1 = (const float*)d_in[14];
  const float* cg1 = (const float*)d_in[15];
  const float* cbe1 = (const float*)d_in[16];
  const float* cw2 = (const float*)d_in[17];
  const float* cb2 = (const float*)d_in[18];
  const float* cg2 = (const float*)d_in[19];
  const float* cbe2 = (const float*)d_in[20];
  const float* cgw = (const float*)d_in[21];
  const float* cgb = (const float*)d_in[22];

  char* ws = (char*)d_ws;
  u16* cw1T  = (u16*)(ws + 0);           // 16 MB  [16][1024][512]
  u16* cw2T  = (u16*)(ws + 16777216);    // 16 MB  [16][512][1024]
  u16* fw1T  = (u16*)(ws + 33554432);    // 1 MB   [1024][512]
  u16* fw2T  = (u16*)(ws + 34603008);    // 1 MB   [512][1024]
  u16* sw1T  = (u16*)(ws + 35651584);    // 512 KB [512][512]
  u16* sw2T  = (u16*)(ws + 36175872);    // 512 KB
  u16* gwT   = (u16*)(ws + 36700160);    // 1 MB   [512][1024]
  u16* xbf   = (u16*)(ws + 37748736);    // 4 MB   [4096][512]
  u16* s1nbf = (u16*)(ws + 41943040);    // 4 MB
  u16* y1bf  = (u16*)(ws + 46137344);    // 8 MB   [4096][1024]
  float* s1f = (float*)(ws + 54525952);  // 8 MB   [4096][512]
  u16* hcat  = (u16*)(ws + 62914560);    // 8 MB   [4096][1024] fast|slow
  float* hF  = (float*)(ws + 71303168);  // 8 MB
  u16* hbf   = (u16*)(ws + 79691776);    // 4 MB
  float* scores = (float*)(ws + 83886080);   // 256 KB
  int* selidx = (int*)(ws + 84148224);       // 16 KB
  int* selcnt = (int*)(ws + 84164608);       // 64 B
  // overlays (liveness-checked):
  float* p2n  = (float*)(ws + 37748736);  // 8 MB over xbf+s1nbf (dead after G3/G4)
  u16* p1bf   = (u16*)(ws + 46137344);    // over y1bf (dead after G2)
  float* p2   = (float*)(ws + 54525952);  // over s1f (dead after LN512)
  int* posmap = (int*)(ws + 62914560);    // 256 KB over hcat (dead after G5)

  dim3 blk(256);
  hipMemsetAsync(selcnt, 0, 64, stream);
  // weight transposes + x convert
  cvt_k<<<2048, blk, 0, stream>>>(x, xbf, 524288);
  transpose_b_k<<<dim3(32, 16, 1), blk, 0, stream>>>(fw1, fw1T, 512, 1024);
  transpose_b_k<<<dim3(16, 32, 1), blk, 0, stream>>>(fw2, fw2T, 1024, 512);
  transpose_b_k<<<dim3(16, 16, 1), blk, 0, stream>>>(sw1, sw1T, 512, 512);
  transpose_b_k<<<dim3(16, 16, 1), blk, 0, stream>>>(sw2, sw2T, 512, 512);
  transpose_b_k<<<dim3(16, 32, 1), blk, 0, stream>>>(gw, gwT, 1024, 512);
  transpose_b_k<<<dim3(32, 16, 16), blk, 0, stream>>>(cw1, cw1T, 512, 1024);
  transpose_b_k<<<dim3(16, 32, 16), blk, 0, stream>>>(cw2, cw2T, 1024, 512);

  // G1: y1 = gelu(x @ fw1)            [4096,1024] bf16
  mgemm_k<0><<<dim3(16, 32, 1), blk, 0, stream>>>(
      xbf, fw1T, fb1, nullptr, y1bf, 1024, nullptr, 4096, 1024, 512, 4096, 0, 0, 0, 0);
  // G2: fast = gelu(y1 @ fw2) -> hcat[:, :512] bf16
  mgemm_k<0><<<dim3(8, 32, 1), blk, 0, stream>>>(
      y1bf, fw2T, fb2, nullptr, hcat, 1024, nullptr, 4096, 512, 1024, 4096, 0, 0, 0, 0);
  // G3: s1 = gelu(x @ sw1)            f32
  mgemm_k<1><<<dim3(8, 32, 1), blk, 0, stream>>>(
      xbf, sw1T, sb1, s1f, nullptr, 0, nullptr, 4096, 512, 512, 4096, 0, 0, 0, 0);
  ln512bf_k<<<1024, blk, 0, stream>>>(s1f, sg, sbeta, s1nbf, 4096);
  // G4: slow = gelu(s1n @ sw2) -> hcat[:, 512:] bf16
  mgemm_k<0><<<dim3(8, 32, 1), blk, 0, stream>>>(
      s1nbf, sw2T, sb2, nullptr, hcat + 512, 1024, nullptr, 4096, 512, 512, 4096, 0, 0, 0, 0);
  // G5: gate + mix + blend -> hF f32, hbf bf16
  mgemm_k<2><<<dim3(8, 32, 1), blk, 0, stream>>>(
      hcat, gwT, gb, hF, hbf, 512, x, 4096, 512, 1024, 4096, 0, 0, 0, 0);
  // posmap overlay (hcat dead after G5): -1 everywhere
  hipMemsetAsync(posmap, 0xFF, 262144, stream);
  // scores + exact top-K (binary search, parallel tie handling)
  scores_k<<<1024, blk, 0, stream>>>(hF, cgw, cgb, scores);
  select_bsearch_k<<<16, blk, 0, stream>>>(scores, selcnt, selidx, posmap);
  // columns (sparse rows only)
  mgemm_col1_k<<<dim3(16, 2, 16), blk, 0, stream>>>(hbf, cw1T, cb1, p1bf, selidx);
  ln1024bf_k<<<dim3(51, 16), blk, 0, stream>>>(p1bf, cg1, cbe1);
  mgemm_k<3><<<dim3(8, 2, 16), blk, 0, stream>>>(
      p1bf, cw2T, cb2, p2, nullptr, 0, nullptr, 256, 512, 1024, KSEL,
      256L * 1024, 512L * 1024, 512, 256L * 512);
  // LN(p2) -> dense p2n (no atomics)
  ln512n_k<<<dim3(51, 16), blk, 0, stream>>>(p2, cg2, cbe2, p2n);
  // out = h + 0.00625 * gather-sum over columns
  final_gather_k<<<1024, blk, 0, stream>>>(hF, p2n, posmap, (float*)d_out);
}

// Round 14
// 339.477 us; speedup vs baseline: 1.3547x; 1.0915x over previous
//
#include <hip/hip_runtime.h>
#include <math.h>

// UnifiedCortexGPT — bf16 MFMA + bsearch top-K + gather reduce
// + 2-phase counted-vmcnt GEMM pipeline + batched prep (1 launch) + no memsets.
// B=4096, D=512, C=16, K_sel=204.

#define KSEL 204

typedef unsigned short u16;
typedef __attribute__((ext_vector_type(8))) short bf16x8;
typedef __attribute__((ext_vector_type(4))) float f32x4;
typedef __attribute__((ext_vector_type(8))) unsigned short u16x8;

__device__ __forceinline__ float gelu_f(float x) {
  return 0.5f * x * (1.0f + erff(x * 0.70710678118654752f));
}
__device__ __forceinline__ u16 f2b(float f) {  // RNE fp32->bf16
  unsigned u = __float_as_uint(f);
  u += 0x7fff + ((u >> 16) & 1);
  return (u16)(u >> 16);
}
__device__ __forceinline__ float b2f(u16 b) {
  return __uint_as_float(((unsigned)b) << 16);
}

#define GLOAD_LDS(gsrc, ldst)                                                  \
  __builtin_amdgcn_global_load_lds(                                            \
      (const __attribute__((address_space(1))) void*)(gsrc),                   \
      (__attribute__((address_space(3))) void*)(ldst), 16, 0, 0)

// ---------- batched prep: 7 weight transposes (f32->bf16T) + x convert ----------
struct PrepDesc {
  const float* src;
  u16* dst;
  int K, N, base, mode;  // mode 0: transpose [K][N]f32 -> [N][K]bf16 (32x32 tiles)
};                       // mode 1: elementwise cvt (256 float4 per block)
struct PrepArgs {
  PrepDesc d[8];
};

__global__ __launch_bounds__(256) void prep_k(PrepArgs a) {
  const int t = blockIdx.x;
  int di = 0;
#pragma unroll
  for (int i = 0; i < 8; i++)
    if (t >= a.d[i].base) di = i;
  const PrepDesc d = a.d[di];
  const int local = t - d.base;
  if (d.mode == 1) {
    int i = local * 256 + threadIdx.x;
    float4 v = ((const float4*)d.src)[i];
    ushort4 o;
    o.x = f2b(v.x); o.y = f2b(v.y); o.z = f2b(v.z); o.w = f2b(v.w);
    ((ushort4*)d.dst)[i] = o;
    return;
  }
  const int ntx = d.N >> 5, nty = d.K >> 5, per = ntx * nty;
  const int slab = local / per, rem = local % per;
  const int n0 = (rem % ntx) << 5, k0 = (rem / ntx) << 5;
  const float* src = d.src + (size_t)slab * d.K * d.N;
  u16* dst = d.dst + (size_t)slab * d.K * d.N;
  __shared__ float tl[32][33];
  const int r = threadIdx.x >> 5, c = threadIdx.x & 31;
#pragma unroll
  for (int i = 0; i < 4; i++)
    tl[r + 8 * i][c] = src[(size_t)(k0 + r + 8 * i) * d.N + n0 + c];
  __syncthreads();
#pragma unroll
  for (int i = 0; i < 4; i++)
    dst[(size_t)(n0 + r + 8 * i) * d.K + k0 + c] = f2b(tl[c][r + 8 * i]);
}

// ================= MFMA GEMM template (2-phase dbuf pipeline) =================
// A [M][K] bf16, Bt [N][K] bf16, tile 128(M)x64(N), BK=64, 4 waves 2x2.
// Per K-step: stage NEXT tile, s_waitcnt vmcnt(6) (counted — prefetch stays in
// flight), raw s_barrier, ds_read+MFMA current, raw s_barrier.
// EPI: 0 gelu->bf16 | 1 gelu->f32 | 2 gate epilogue | 3 gelu->f32 row-masked
template <int EPI>
__global__ __launch_bounds__(256) void mgemm_k(
    const u16* __restrict__ A, const u16* __restrict__ Bt,
    const float* __restrict__ bias, float* __restrict__ outF,
    u16* __restrict__ outB, int ldOutB, const float* __restrict__ xres,
    int M, int N, int K, int Mvalid,
    long szA, long szB, long szBias, long szOutF) {
  __shared__ __align__(16) u16 As[2][128 * 64];  // 32KB
  __shared__ __align__(16) u16 Bs[2][64 * 64];   // 16KB
  const int tid = threadIdx.x;
  const int wid = tid >> 6, lane = tid & 63;
  const int wm = wid & 1, wn = wid >> 1;
  const int row0 = blockIdx.y * 128, col0 = blockIdx.x * 64;
  const size_t z = blockIdx.z;
  const u16* Ap = A + z * szA;
  const u16* Bp = Bt + z * szB;
  const float* biasp = bias + z * szBias;

  const int srow = tid >> 3;
  const int sslot = (tid & 7) ^ (srow & 7);

  f32x4 acc[4][2];
#pragma unroll
  for (int mi = 0; mi < 4; mi++)
#pragma unroll
    for (int ni = 0; ni < 2; ni++) acc[mi][ni] = (f32x4){0.f, 0.f, 0.f, 0.f};

  const int q = lane >> 4, rl = lane & 15;
  const int nt = K >> 6;

  // prologue: stage tile 0 -> buf 0 (6 global_load_lds per wave)
#pragma unroll
  for (int i = 0; i < 4; i++) {
    const u16* src = Ap + (size_t)(row0 + i * 32 + srow) * K + sslot * 8;
    GLOAD_LDS(src, (char*)As + i * 4096 + wid * 1024);
  }
#pragma unroll
  for (int i = 0; i < 2; i++) {
    const u16* src = Bp + (size_t)(col0 + i * 32 + srow) * K + sslot * 8;
    GLOAD_LDS(src, (char*)Bs + i * 4096 + wid * 1024);
  }

  for (int t = 0; t < nt; ++t) {
    const int cur = t & 1;
    if (t + 1 < nt) {
      const int k0 = (t + 1) << 6;
      char* Ad = (char*)As + (cur ^ 1) * 16384;
      char* Bd = (char*)Bs + (cur ^ 1) * 8192;
#pragma unroll
      for (int i = 0; i < 4; i++) {
        const u16* src = Ap + (size_t)(row0 + i * 32 + srow) * K + k0 + sslot * 8;
        GLOAD_LDS(src, Ad + i * 4096 + wid * 1024);
      }
#pragma unroll
      for (int i = 0; i < 2; i++) {
        const u16* src = Bp + (size_t)(col0 + i * 32 + srow) * K + k0 + sslot * 8;
        GLOAD_LDS(src, Bd + i * 4096 + wid * 1024);
      }
      asm volatile("s_waitcnt vmcnt(6)" ::: "memory");  // cur's 6 retired
    } else {
      asm volatile("s_waitcnt vmcnt(0)" ::: "memory");
    }
    __builtin_amdgcn_s_barrier();
    const char* Ar = (const char*)As + cur * 16384;
    const char* Br = (const char*)Bs + cur * 8192;
#pragma unroll
    for (int h = 0; h < 2; h++) {
      bf16x8 af[4], bfr[2];
#pragma unroll
      for (int mi = 0; mi < 4; mi++) {
        int row = wm * 64 + mi * 16 + rl;
        int slot = (h * 4 + q) ^ (row & 7);
        af[mi] = *(const bf16x8*)(Ar + row * 128 + slot * 16);
      }
#pragma unroll
      for (int ni = 0; ni < 2; ni++) {
        int n = wn * 32 + ni * 16 + rl;
        int slot = (h * 4 + q) ^ (n & 7);
        bfr[ni] = *(const bf16x8*)(Br + n * 128 + slot * 16);
      }
#pragma unroll
      for (int mi = 0; mi < 4; mi++)
#pragma unroll
        for (int ni = 0; ni < 2; ni++)
          acc[mi][ni] = __builtin_amdgcn_mfma_f32_16x16x32_bf16(
              af[mi], bfr[ni], acc[mi][ni], 0, 0, 0);
    }
    if (t + 1 < nt) __builtin_amdgcn_s_barrier();  // reads done before overwrite
  }

  // epilogue: C frag layout col = lane&15, row = (lane>>4)*4 + r
#pragma unroll
  for (int ni = 0; ni < 2; ni++) {
    const int col = col0 + wn * 32 + ni * 16 + rl;
    const float bv = biasp[col];
#pragma unroll
    for (int mi = 0; mi < 4; mi++) {
#pragma unroll
      for (int r = 0; r < 4; r++) {
        const int row = row0 + wm * 64 + mi * 16 + q * 4 + r;
        float v = acc[mi][ni][r] + bv;
        if (EPI == 0) {
          outB[(size_t)row * ldOutB + col] = f2b(gelu_f(v));
        } else if (EPI == 1) {
          (outF + z * szOutF)[(size_t)row * N + col] = gelu_f(v);
        } else if (EPI == 2) {
          float g = 1.f / (1.f + expf(-v));
          float fa = b2f(Ap[(size_t)row * 1024 + col]);
          float sl = b2f(Ap[(size_t)row * 1024 + 512 + col]);
          float xv = xres[(size_t)row * 512 + col];
          float hv = g * (0.91f * fa + 0.09f * sl) + (1.f - g) * xv;
          outF[(size_t)row * 512 + col] = hv;
          outB[(size_t)row * 512 + col] = f2b(hv);
        } else {  // EPI == 3
          if (row < Mvalid)
            (outF + z * szOutF)[(size_t)row * N + col] = gelu_f(v);
        }
      }
    }
  }
}

// ---------- column GEMM 1 with row gather (same 2-phase pipeline) ----------
__global__ __launch_bounds__(256) void mgemm_col1_k(
    const u16* __restrict__ hbf, const u16* __restrict__ cw1T,
    const float* __restrict__ cb1, u16* __restrict__ p1bf,
    const int* __restrict__ selidx) {
  const int N = 1024, K = 512;
  __shared__ __align__(16) u16 As[2][128 * 64];
  __shared__ __align__(16) u16 Bs[2][64 * 64];
  const int tid = threadIdx.x;
  const int wid = tid >> 6, lane = tid & 63;
  const int wm = wid & 1, wn = wid >> 1;
  const int row0 = blockIdx.y * 128, col0 = blockIdx.x * 64;
  const int c = blockIdx.z;
  const u16* Bp = cw1T + (size_t)c * N * K;
  const float* biasp = cb1 + (size_t)c * N;
  u16* outp = p1bf + (size_t)c * 256 * N;
  const int* rmap = selidx + c * 256;

  const int srow = tid >> 3;
  const int sslot = (tid & 7) ^ (srow & 7);
  int gr[4];
#pragma unroll
  for (int i = 0; i < 4; i++) {
    int rli = row0 + i * 32 + srow;
    gr[i] = (rli < KSEL) ? rmap[rli] : 0;
  }

  f32x4 acc[4][2];
#pragma unroll
  for (int mi = 0; mi < 4; mi++)
#pragma unroll
    for (int ni = 0; ni < 2; ni++) acc[mi][ni] = (f32x4){0.f, 0.f, 0.f, 0.f};
  const int q = lane >> 4, rl = lane & 15;
  const int nt = K >> 6;  // 8

  // prologue: tile 0 -> buf 0
#pragma unroll
  for (int i = 0; i < 4; i++) {
    const u16* src = hbf + (size_t)gr[i] * 512 + sslot * 8;
    GLOAD_LDS(src, (char*)As + i * 4096 + wid * 1024);
  }
#pragma unroll
  for (int i = 0; i < 2; i++) {
    const u16* src = Bp + (size_t)(col0 + i * 32 + srow) * K + sslot * 8;
    GLOAD_LDS(src, (char*)Bs + i * 4096 + wid * 1024);
  }

  for (int t = 0; t < nt; ++t) {
    const int cur = t & 1;
    if (t + 1 < nt) {
      const int k0 = (t + 1) << 6;
      char* Ad = (char*)As + (cur ^ 1) * 16384;
      char* Bd = (char*)Bs + (cur ^ 1) * 8192;
#pragma unroll
      for (int i = 0; i < 4; i++) {
        const u16* src = hbf + (size_t)gr[i] * 512 + k0 + sslot * 8;
        GLOAD_LDS(src, Ad + i * 4096 + wid * 1024);
      }
#pragma unroll
      for (int i = 0; i < 2; i++) {
        const u16* src = Bp + (size_t)(col0 + i * 32 + srow) * K + k0 + sslot * 8;
        GLOAD_LDS(src, Bd + i * 4096 + wid * 1024);
      }
      asm volatile("s_waitcnt vmcnt(6)" ::: "memory");
    } else {
      asm volatile("s_waitcnt vmcnt(0)" ::: "memory");
    }
    __builtin_amdgcn_s_barrier();
    const char* Ar = (const char*)As + cur * 16384;
    const char* Br = (const char*)Bs + cur * 8192;
#pragma unroll
    for (int h = 0; h < 2; h++) {
      bf16x8 af[4], bfr[2];
#pragma unroll
      for (int mi = 0; mi < 4; mi++) {
        int row = wm * 64 + mi * 16 + rl;
        int slot = (h * 4 + q) ^ (row & 7);
        af[mi] = *(const bf16x8*)(Ar + row * 128 + slot * 16);
      }
#pragma unroll
      for (int ni = 0; ni < 2; ni++) {
        int n = wn * 32 + ni * 16 + rl;
        int slot = (h * 4 + q) ^ (n & 7);
        bfr[ni] = *(const bf16x8*)(Br + n * 128 + slot * 16);
      }
#pragma unroll
      for (int mi = 0; mi < 4; mi++)
#pragma unroll
        for (int ni = 0; ni < 2; ni++)
          acc[mi][ni] = __builtin_amdgcn_mfma_f32_16x16x32_bf16(
              af[mi], bfr[ni], acc[mi][ni], 0, 0, 0);
    }
    if (t + 1 < nt) __builtin_amdgcn_s_barrier();
  }

#pragma unroll
  for (int ni = 0; ni < 2; ni++) {
    const int col = col0 + wn * 32 + ni * 16 + rl;
    const float bv = biasp[col];
#pragma unroll
    for (int mi = 0; mi < 4; mi++) {
#pragma unroll
      for (int r = 0; r < 4; r++) {
        const int row = row0 + wm * 64 + mi * 16 + q * 4 + r;
        if (row < KSEL)
          outp[(size_t)row * N + col] = f2b(gelu_f(acc[mi][ni][r] + bv));
      }
    }
  }
}

// ---------------- LayerNorm 512 f32 -> bf16 (slow path) ----------------
__global__ __launch_bounds__(256) void ln512bf_k(
    const float* __restrict__ in, const float* __restrict__ g,
    const float* __restrict__ b, u16* __restrict__ out, int nrows) {
  int wave = threadIdx.x >> 6, lane = threadIdx.x & 63;
  int row = blockIdx.x * 4 + wave;
  if (row >= nrows) return;
  const float4* r4 = (const float4*)(in + (size_t)row * 512);
  float4 v0 = r4[lane * 2], v1 = r4[lane * 2 + 1];
  float s = v0.x + v0.y + v0.z + v0.w + v1.x + v1.y + v1.z + v1.w;
#pragma unroll
  for (int o = 32; o; o >>= 1) s += __shfl_xor(s, o);
  float mean = s * (1.0f / 512.0f);
  float qv = 0.f;
  {
    float dx;
    dx = v0.x - mean; qv += dx * dx;  dx = v0.y - mean; qv += dx * dx;
    dx = v0.z - mean; qv += dx * dx;  dx = v0.w - mean; qv += dx * dx;
    dx = v1.x - mean; qv += dx * dx;  dx = v1.y - mean; qv += dx * dx;
    dx = v1.z - mean; qv += dx * dx;  dx = v1.w - mean; qv += dx * dx;
  }
#pragma unroll
  for (int o = 32; o; o >>= 1) qv += __shfl_xor(qv, o);
  float rstd = rsqrtf(qv * (1.0f / 512.0f) + 1e-5f);
  const float4* g4 = (const float4*)g;
  const float4* b4 = (const float4*)b;
  float4 gg0 = g4[lane * 2], gg1 = g4[lane * 2 + 1];
  float4 bb0 = b4[lane * 2], bb1 = b4[lane * 2 + 1];
  u16x8 o8;
  o8[0] = f2b((v0.x - mean) * rstd * gg0.x + bb0.x);
  o8[1] = f2b((v0.y - mean) * rstd * gg0.y + bb0.y);
  o8[2] = f2b((v0.z - mean) * rstd * gg0.z + bb0.z);
  o8[3] = f2b((v0.w - mean) * rstd * gg0.w + bb0.w);
  o8[4] = f2b((v1.x - mean) * rstd * gg1.x + bb1.x);
  o8[5] = f2b((v1.y - mean) * rstd * gg1.y + bb1.y);
  o8[6] = f2b((v1.z - mean) * rstd * gg1.z + bb1.z);
  o8[7] = f2b((v1.w - mean) * rstd * gg1.w + bb1.w);
  *(u16x8*)(out + (size_t)row * 512 + lane * 8) = o8;
}

// ---------------- LayerNorm 1024 in-place on bf16 p1, per-column g/b ----------------
__global__ __launch_bounds__(256) void ln1024bf_k(
    u16* __restrict__ p, const float* __restrict__ g,
    const float* __restrict__ b) {
  int wave = threadIdx.x >> 6, lane = threadIdx.x & 63;
  int row = blockIdx.x * 4 + wave;
  int c = blockIdx.y;
  if (row >= KSEL) return;
  u16* rp = p + ((size_t)c * 256 + row) * 1024 + lane * 16;
  u16x8 a0 = *(const u16x8*)rp;
  u16x8 a1 = *(const u16x8*)(rp + 8);
  float f[16];
#pragma unroll
  for (int j = 0; j < 8; j++) { f[j] = b2f(a0[j]); f[8 + j] = b2f(a1[j]); }
  float s = 0.f;
#pragma unroll
  for (int j = 0; j < 16; j++) s += f[j];
#pragma unroll
  for (int o = 32; o; o >>= 1) s += __shfl_xor(s, o);
  float mean = s * (1.0f / 1024.0f);
  float qv = 0.f;
#pragma unroll
  for (int j = 0; j < 16; j++) { float d = f[j] - mean; qv += d * d; }
#pragma unroll
  for (int o = 32; o; o >>= 1) qv += __shfl_xor(qv, o);
  float rstd = rsqrtf(qv * (1.0f / 1024.0f) + 1e-5f);
  const float* gp = g + (size_t)c * 1024 + lane * 16;
  const float* bp = b + (size_t)c * 1024 + lane * 16;
  u16x8 o0, o1;
#pragma unroll
  for (int j = 0; j < 8; j++)
    o0[j] = f2b((f[j] - mean) * rstd * gp[j] + bp[j]);
#pragma unroll
  for (int j = 0; j < 8; j++)
    o1[j] = f2b((f[8 + j] - mean) * rstd * gp[8 + j] + bp[8 + j]);
  *(u16x8*)rp = o0;
  *(u16x8*)(rp + 8) = o1;
}

// ---------- LayerNorm 512 on p2 f32, per-column g/b, DENSE write to p2n ----------
__global__ __launch_bounds__(256) void ln512n_k(
    const float* __restrict__ p2, const float* __restrict__ g,
    const float* __restrict__ b, float* __restrict__ p2n) {
  int wave = threadIdx.x >> 6, lane = threadIdx.x & 63;
  int row = blockIdx.x * 4 + wave;
  int c = blockIdx.y;
  if (row >= KSEL) return;
  const float4* r4 = (const float4*)(p2 + ((size_t)c * 256 + row) * 512);
  float4 v0 = r4[lane * 2], v1 = r4[lane * 2 + 1];
  float s = v0.x + v0.y + v0.z + v0.w + v1.x + v1.y + v1.z + v1.w;
#pragma unroll
  for (int o = 32; o; o >>= 1) s += __shfl_xor(s, o);
  float mean = s * (1.0f / 512.0f);
  float qv = 0.f;
  {
    float dx;
    dx = v0.x - mean; qv += dx * dx;  dx = v0.y - mean; qv += dx * dx;
    dx = v0.z - mean; qv += dx * dx;  dx = v0.w - mean; qv += dx * dx;
    dx = v1.x - mean; qv += dx * dx;  dx = v1.y - mean; qv += dx * dx;
    dx = v1.z - mean; qv += dx * dx;  dx = v1.w - mean; qv += dx * dx;
  }
#pragma unroll
  for (int o = 32; o; o >>= 1) qv += __shfl_xor(qv, o);
  float rstd = rsqrtf(qv * (1.0f / 512.0f) + 1e-5f);
  const float4* g4 = (const float4*)(g + (size_t)c * 512);
  const float4* b4 = (const float4*)(b + (size_t)c * 512);
  float4 gg0 = g4[lane * 2], gg1 = g4[lane * 2 + 1];
  float4 bb0 = b4[lane * 2], bb1 = b4[lane * 2 + 1];
  float4 o0, o1;
  o0.x = (v0.x - mean) * rstd * gg0.x + bb0.x;
  o0.y = (v0.y - mean) * rstd * gg0.y + bb0.y;
  o0.z = (v0.z - mean) * rstd * gg0.z + bb0.z;
  o0.w = (v0.w - mean) * rstd * gg0.w + bb0.w;
  o1.x = (v1.x - mean) * rstd * gg1.x + bb1.x;
  o1.y = (v1.y - mean) * rstd * gg1.y + bb1.y;
  o1.z = (v1.z - mean) * rstd * gg1.z + bb1.z;
  o1.w = (v1.w - mean) * rstd * gg1.w + bb1.w;
  float4* w4 = (float4*)(p2n + ((size_t)c * 256 + row) * 512);
  w4[lane * 2] = o0;
  w4[lane * 2 + 1] = o1;
}

// ---------------- scores[c][b] = h[b] . colg_w[c] + colg_b[c] ----------------
__global__ __launch_bounds__(256) void scores_k(
    const float* __restrict__ h, const float* __restrict__ cw,
    const float* __restrict__ cb, float* __restrict__ scores) {
  int wave = threadIdx.x >> 6, lane = threadIdx.x & 63;
  int b = blockIdx.x * 4 + wave;
  const float4* hr = (const float4*)(h + (size_t)b * 512);
  float4 h0 = hr[lane * 2], h1 = hr[lane * 2 + 1];
#pragma unroll
  for (int c = 0; c < 16; c++) {
    const float4* w4 = (const float4*)(cw + (size_t)c * 512);
    float4 w0 = w4[lane * 2], w1 = w4[lane * 2 + 1];
    float acc = h0.x * w0.x + h0.y * w0.y + h0.z * w0.z + h0.w * w0.w +
                h1.x * w1.x + h1.y * w1.y + h1.z * w1.z + h1.w * w1.w;
#pragma unroll
    for (int o = 32; o; o >>= 1) acc += __shfl_xor(acc, o);
    if (lane == 0) scores[c * 4096 + b] = acc + cb[c];
  }
}

// -------- exact top-K via 32-step binary search; parallel tie handling --------
// LDS position counter (no global selcnt); block initializes its own posmap
// segment to -1 (no host memset needed).
__global__ __launch_bounds__(256) void select_bsearch_k(
    const float* __restrict__ scores, int* __restrict__ selidx,
    int* __restrict__ posmap) {
  const int c = blockIdx.x;
  const int t = threadIdx.x;
  const int w = t >> 6, lane = t & 63;
  __shared__ unsigned keys[4096];
  __shared__ int wc[2][4];
  __shared__ int cnt;
  unsigned k[16];
#pragma unroll
  for (int i = 0; i < 16; i++) {
    unsigned u = __float_as_uint(scores[c * 4096 + t + 256 * i]);
    u = (u & 0x80000000u) ? ~u : (u | 0x80000000u);  // monotonic key
    k[i] = u;
    keys[t + 256 * i] = u;
    posmap[c * 4096 + t + 256 * i] = -1;  // init own segment
  }
  if (t == 0) cnt = 0;
  __syncthreads();
  // find T = K-th largest key: max T s.t. count(>=T) >= KSEL
  unsigned lo = 0u, hi = 0xFFFFFFFFu;
  for (int it = 0; it < 32; ++it) {
    const unsigned mid = hi - ((hi - lo) >> 1);  // upper mid, no overflow
    int cntv = 0;
#pragma unroll
    for (int i = 0; i < 16; i++) cntv += (k[i] >= mid);
#pragma unroll
    for (int o = 32; o; o >>= 1) cntv += __shfl_xor(cntv, o);
    if (lane == 0) wc[it & 1][w] = cntv;
    __syncthreads();
    const int tot = wc[it & 1][0] + wc[it & 1][1] + wc[it & 1][2] + wc[it & 1][3];
    if (tot >= KSEL) lo = mid; else hi = mid - 1;  // identical on all threads
  }
  const unsigned T = lo;
  // packed block-wide counts: (count_gt << 16) | count_eq
  {
    int cg = 0, ce = 0;
#pragma unroll
    for (int i = 0; i < 16; i++) { cg += (k[i] > T); ce += (k[i] == T); }
    int packed = (cg << 16) | ce;
#pragma unroll
    for (int o = 32; o; o >>= 1) packed += __shfl_xor(packed, o);
    if (lane == 0) wc[0][w] = packed;
  }
  __syncthreads();
  const int ptot = wc[0][0] + wc[0][1] + wc[0][2] + wc[0][3];
  const int count_gt = ptot >> 16;
  const int count_eq = ptot & 0xFFFF;
  const int need_eq = KSEL - count_gt;               // 1 <= need_eq <= count_eq
  const bool take_all_ties = (count_eq == need_eq);  // true for distinct scores
#pragma unroll
  for (int i = 0; i < 16; i++) {
    const int b = t + 256 * i;
    bool sel = (k[i] > T);
    if (k[i] == T) {
      if (take_all_ties) {
        sel = true;
      } else {  // genuine duplicate threshold: rank ties by lower index (rare)
        int r = 0;
        for (int j = 0; j < b; j++) r += (keys[j] == T);
        sel = (r < need_eq);
      }
    }
    if (sel) {
      int pos = atomicAdd(&cnt, 1);
      selidx[c * 256 + pos] = b;
      posmap[c * 4096 + b] = pos;
    }
  }
}

// ---------------- out[b] = h[b] + 0.00625 * sum_c p2n[c][posmap[c][b]] ----------------
__global__ __launch_bounds__(256) void final_gather_k(
    const float* __restrict__ h, const float* __restrict__ p2n,
    const int* __restrict__ posmap, float* __restrict__ out) {
  int wave = threadIdx.x >> 6, lane = threadIdx.x & 63;
  int b = blockIdx.x * 4 + wave;
  float4 a0 = {0.f, 0.f, 0.f, 0.f}, a1 = {0.f, 0.f, 0.f, 0.f};
#pragma unroll
  for (int c = 0; c < 16; c++) {
    int pos = posmap[c * 4096 + b];  // wave-uniform
    if (pos >= 0) {
      const float4* r = (const float4*)(p2n + ((size_t)c * 256 + pos) * 512);
      float4 v0 = r[lane * 2], v1 = r[lane * 2 + 1];
      a0.x += v0.x; a0.y += v0.y; a0.z += v0.z; a0.w += v0.w;
      a1.x += v1.x; a1.y += v1.y; a1.z += v1.z; a1.w += v1.w;
    }
  }
  const float4* hr = (const float4*)(h + (size_t)b * 512);
  float4 h0 = hr[lane * 2], h1 = hr[lane * 2 + 1];
  float4 o0, o1;
  o0.x = h0.x + 0.00625f * a0.x;  o0.y = h0.y + 0.00625f * a0.y;
  o0.z = h0.z + 0.00625f * a0.z;  o0.w = h0.w + 0.00625f * a0.w;
  o1.x = h1.x + 0.00625f * a1.x;  o1.y = h1.y + 0.00625f * a1.y;
  o1.z = h1.z + 0.00625f * a1.z;  o1.w = h1.w + 0.00625f * a1.w;
  float4* w4 = (float4*)(out + (size_t)b * 512);
  w4[lane * 2] = o0;
  w4[lane * 2 + 1] = o1;
}

extern "C" void kernel_launch(void* const* d_in, const int* in_sizes, int n_in,
                              void* d_out, int out_size, void* d_ws,
                              size_t ws_size, hipStream_t stream) {
  const float* x = (const float*)d_in[0];
  const float* fw1 = (const float*)d_in[1];
  const float* fb1 = (const float*)d_in[2];
  const float* fw2 = (const float*)d_in[3];
  const float* fb2 = (const float*)d_in[4];
  const float* sw1 = (const float*)d_in[5];
  const float* sb1 = (const float*)d_in[6];
  const float* sg = (const float*)d_in[7];
  const float* sbeta = (const float*)d_in[8];
  const float* sw2 = (const float*)d_in[9];
  const float* sb2 = (const float*)d_in[10];
  const float* gw = (const float*)d_in[11];
  const float* gb = (const float*)d_in[12];
  const float* cw1 = (const float*)d_in[13];
  const float* cb1 = (const float*)d_in[14];
  const float* cg1 = (const float*)d_in[15];
  const float* cbe1 = (const float*)d_in[16];
  const float* cw2 = (const float*)d_in[17];
  const float* cb2 = (const float*)d_in[18];
  const float* cg2 = (const float*)d_in[19];
  const float* cbe2 = (const float*)d_in[20];
  const float* cgw = (const float*)d_in[21];
  const float* cgb = (const float*)d_in[22];

  char* ws = (char*)d_ws;
  u16* cw1T  = (u16*)(ws + 0);           // 16 MB  [16][1024][512]
  u16* cw2T  = (u16*)(ws + 16777216);    // 16 MB  [16][512][1024]
  u16* fw1T  = (u16*)(ws + 33554432);    // 1 MB   [1024][512]
  u16* fw2T  = (u16*)(ws + 34603008);    // 1 MB   [512][1024]
  u16* sw1T  = (u16*)(ws + 35651584);    // 512 KB [512][512]
  u16* sw2T  = (u16*)(ws + 36175872);    // 512 KB
  u16* gwT   = (u16*)(ws + 36700160);    // 1 MB   [512][1024]
  u16* xbf   = (u16*)(ws + 37748736);    // 4 MB   [4096][512]
  u16* s1nbf = (u16*)(ws + 41943040);    // 4 MB
  u16* y1bf  = (u16*)(ws + 46137344);    // 8 MB   [4096][1024]
  float* s1f = (float*)(ws + 54525952);  // 8 MB   [4096][512]
  u16* hcat  = (u16*)(ws + 62914560);    // 8 MB   [4096][1024] fast|slow
  float* hF  = (float*)(ws + 71303168);  // 8 MB
  u16* hbf   = (u16*)(ws + 79691776);    // 4 MB
  float* scores = (float*)(ws + 83886080);   // 256 KB
  int* selidx = (int*)(ws + 84148224);       // 16 KB
  // overlays (liveness-checked):
  float* p2n  = (float*)(ws + 37748736);  // 8 MB over xbf+s1nbf (dead after G3/G4)
  u16* p1bf   = (u16*)(ws + 46137344);    // over y1bf (dead after G2)
  float* p2   = (float*)(ws + 54525952);  // over s1f (dead after LN512)
  int* posmap = (int*)(ws + 62914560);    // 256 KB over hcat (dead after G5)

  dim3 blk(256);
  // batched prep: 7 weight transposes + x cvt in ONE launch
  PrepArgs pa;
  pa.d[0] = {fw1, fw1T, 512, 1024, 0, 0};       // 512 tiles
  pa.d[1] = {fw2, fw2T, 1024, 512, 512, 0};     // 512
  pa.d[2] = {sw1, sw1T, 512, 512, 1024, 0};     // 256
  pa.d[3] = {sw2, sw2T, 512, 512, 1280, 0};     // 256
  pa.d[4] = {gw, gwT, 1024, 512, 1536, 0};      // 512
  pa.d[5] = {cw1, cw1T, 512, 1024, 2048, 0};    // 16 slabs -> 8192
  pa.d[6] = {cw2, cw2T, 1024, 512, 10240, 0};   // 8192
  pa.d[7] = {x, (u16*)xbf, 0, 0, 18432, 1};     // 2048 cvt blocks
  prep_k<<<20480, blk, 0, stream>>>(pa);

  // G1: y1 = gelu(x @ fw1)            [4096,1024] bf16
  mgemm_k<0><<<dim3(16, 32, 1), blk, 0, stream>>>(
      xbf, fw1T, fb1, nullptr, y1bf, 1024, nullptr, 4096, 1024, 512, 4096, 0, 0, 0, 0);
  // G2: fast = gelu(y1 @ fw2) -> hcat[:, :512] bf16
  mgemm_k<0><<<dim3(8, 32, 1), blk, 0, stream>>>(
      y1bf, fw2T, fb2, nullptr, hcat, 1024, nullptr, 4096, 512, 1024, 4096, 0, 0, 0, 0);
  // G3: s1 = gelu(x @ sw1)            f32
  mgemm_k<1><<<dim3(8, 32, 1), blk, 0, stream>>>(
      xbf, sw1T, sb1, s1f, nullptr, 0, nullptr, 4096, 512, 512, 4096, 0, 0, 0, 0);
  ln512bf_k<<<1024, blk, 0, stream>>>(s1f, sg, sbeta, s1nbf, 4096);
  // G4: slow = gelu(s1n @ sw2) -> hcat[:, 512:] bf16
  mgemm_k<0><<<dim3(8, 32, 1), blk, 0, stream>>>(
      s1nbf, sw2T, sb2, nullptr, hcat + 512, 1024, nullptr, 4096, 512, 512, 4096, 0, 0, 0, 0);
  // G5: gate + mix + blend -> hF f32, hbf bf16
  mgemm_k<2><<<dim3(8, 32, 1), blk, 0, stream>>>(
      hcat, gwT, gb, hF, hbf, 512, x, 4096, 512, 1024, 4096, 0, 0, 0, 0);
  // scores + exact top-K (binary search; inits its own posmap, LDS counter)
  scores_k<<<1024, blk, 0, stream>>>(hF, cgw, cgb, scores);
  select_bsearch_k<<<16, blk, 0, stream>>>(scores, selidx, posmap);
  // columns (sparse rows only)
  mgemm_col1_k<<<dim3(16, 2, 16), blk, 0, stream>>>(hbf, cw1T, cb1, p1bf, selidx);
  ln1024bf_k<<<dim3(51, 16), blk, 0, stream>>>(p1bf, cg1, cbe1);
  mgemm_k<3><<<dim3(8, 2, 16), blk, 0, stream>>>(
      p1bf, cw2T, cb2, p2, nullptr, 0, nullptr, 256, 512, 1024, KSEL,
      256L * 1024, 512L * 1024, 512, 256L * 512);
  // LN(p2) -> dense p2n (no atomics)
  ln512n_k<<<dim3(51, 16), blk, 0, stream>>>(p2, cg2, cbe2, p2n);
  // out = h + 0.00625 * gather-sum over columns
  final_gather_k<<<1024, blk, 0, stream>>>(hF, p2n, posmap, (float*)d_out);
}